// Round 2
// baseline (217.456 us; speedup 1.0000x reference)
//
#include <hip/hip_runtime.h>
#include <hip/hip_bf16.h>

// Gaussian-kernel regression, fused flash-attention style. 3-kernel structure.
// K_prep: 512 one-wave blocks: 256x yt=y@R^T+t GEMM -> KA2C*yt perm + yn hi/lo
//   folded into K=144 slot; 256x V=X[1:] transpose perm.
// K_main (round-7): M=64 per wave (2 query fragments share every A-chunk read)
//   -> LDS ds_read traffic per MFMA halved (was the top pipe at ~22us/CU).
//   Block = 256 rows, grid (32, js=16) = 512 blocks = 2/CU, launch_bounds(256,2).
//   Per tile: S(0) exp0 PV(0) S(1) exp1 | BAR | stage yt+Vlo | PV(1) | BAR |
//   stage Vhi.  Region-race audit: yt restaged after S(1); Vlo after PV(0);
//   Vhi after PV(1); each stage drains at the next barrier before consumers.
// K_fin : grid (128,4)=512 blocks, sp-loop unrolled x4 -> pipelined 64MB read.
// NOTE (R9, prior session): grid-wide barriers w/ agent-scope fences on gfx950
// = L2 writeback storms, 12x slowdown. Never again.

#define LOG2E 1.44269504088896340736f
#define KNEG (-(1.0f/256.0f)*LOG2E)
#define KA2C (2.0f*(1.0f/256.0f)*LOG2E)

typedef __attribute__((ext_vector_type(4)))  float f32x4;
typedef __attribute__((ext_vector_type(16))) float f32x16;
typedef __attribute__((ext_vector_type(8)))  short bf16x8;

__device__ __forceinline__ unsigned short f2bf(float f) {
  unsigned u = __builtin_bit_cast(unsigned, f);
  u = (u + 0x7fffu + ((u >> 16) & 1u)) >> 16;  // RNE; inputs finite
  return (unsigned short)u;
}
__device__ __forceinline__ unsigned pk2bf(float a, float b) {
  __hip_bfloat162 h = __float22bfloat162_rn(float2{a, b});  // v_cvt_pk_bf16_f32
  unsigned u;
  __builtin_memcpy(&u, &h, 4);
  return u;
}
__device__ __forceinline__ bf16x8 pack8(float4 p0, float4 p1) {
  uint4 u;
  u.x = pk2bf(p0.x, p0.y); u.y = pk2bf(p0.z, p0.w);
  u.z = pk2bf(p1.x, p1.y); u.w = pk2bf(p1.z, p1.w);
  return __builtin_bit_cast(bf16x8, u);
}
__device__ __forceinline__ float fast_exp2(float x) {
#if __has_builtin(__builtin_amdgcn_exp2f)
  return __builtin_amdgcn_exp2f(x);
#else
  return exp2f(x);
#endif
}
__device__ __forceinline__ void gl2lds16(const void* g, void* l) {
  __builtin_amdgcn_global_load_lds((const __attribute__((address_space(1))) unsigned int*)g,
                                   (__attribute__((address_space(3))) unsigned int*)l, 16, 0, 0);
}
__device__ __forceinline__ f32x16 mfma_32x32x16(bf16x8 a, bf16x8 b, f32x16 c) {
  return __builtin_amdgcn_mfma_f32_32x32x16_bf16(a, b, c, 0, 0, 0);
}
// Exchanges a's high 32 lanes with b's low 32 lanes (gfx950 permlane32_swap).
__device__ __forceinline__ void pl32swap(unsigned &a, unsigned &b) {
#if __has_builtin(__builtin_amdgcn_permlane32_swap)
  auto r = __builtin_amdgcn_permlane32_swap((int)a, (int)b, false, false);
  a = (unsigned)r[0];
  b = (unsigned)r[1];
#else
  unsigned pa = (unsigned)__shfl_xor((int)a, 32, 64);
  unsigned pb = (unsigned)__shfl_xor((int)b, 32, 64);
  bool hi = (threadIdx.x & 32) != 0;
  unsigned na = hi ? pb : a;
  unsigned nb = hi ? b  : pa;
  a = na; b = nb;
#endif
}

#define T_STRIDE 34816   // per-64j-tile bytes: 2 jc x 9 kc x 1024 (yt) + 16384 (V)
#define V_OFF    18432

// ---------------- K_prep: 512 one-wave blocks ----------------
// task = blockIdx.x. task<256: yt GEMM for 32 rows (tile task>>1, half task&1).
// task>=256: V transpose for 32 X1-rows.
__global__ __launch_bounds__(64) void k_prep(const float* __restrict__ y,
                                             const float* __restrict__ R,
                                             const float* __restrict__ t,
                                             const float* __restrict__ X,
                                             unsigned short* __restrict__ ctp) {
  __shared__ char slice[8704];
  const int task = blockIdx.x;
  const int ln = threadIdx.x;
  const int l = ln & 31, h = ln >> 5;

  if (task < 256) {
    // ---- yt task: rows rw..rw+31; tile T=task>>1, jc half jcw=task&1 ----
    unsigned short* ytt = (unsigned short*)slice;        // [32][132] = 8448 B
    float* ynf = (float*)(slice + 8448);                 // 32 floats
    const int T = task >> 1, jcw = task & 1;
    const int rw = task * 32;
    bf16x8 af[8];
    {
      int row = rw + l; if (row > 8190) row = 8190;
      const float* yr = y + (size_t)row * 128;
#pragma unroll
      for (int kc = 0; kc < 8; ++kc) {
        float4 p0 = *(const float4*)(yr + kc*16 + 8*h);
        float4 p1 = *(const float4*)(yr + kc*16 + 8*h + 4);
        af[kc] = pack8(p0, p1);
      }
    }
    f32x16 ac[4];
#pragma unroll
    for (int cc=0; cc<4; ++cc)
#pragma unroll
      for (int i=0;i<16;++i) ac[cc][i] = 0.f;
#pragma unroll
    for (int cc=0; cc<4; ++cc) {
      const float* Rr = R + (size_t)(cc*32 + l) * 128;   // R^T[k][c] = R[c][k]
#pragma unroll
      for (int kc=0; kc<8; ++kc) {
        float4 p0 = *(const float4*)(Rr + kc*16 + 8*h);
        float4 p1 = *(const float4*)(Rr + kc*16 + 8*h + 4);
        ac[cc] = mfma_32x32x16(af[kc], pack8(p0, p1), ac[cc]);
      }
    }
    // D: lane holds yt[rw + (r&3)+8*(r>>2)+4h][cc*32 + l]
    float tv0 = t[l], tv1 = t[32+l], tv2 = t[64+l], tv3 = t[96+l];
    float v0[16], v1[16], v2[16], v3[16], ssq[16];
#pragma unroll
    for (int r=0;r<16;++r) {
      v0[r]=ac[0][r]+tv0; v1[r]=ac[1][r]+tv1; v2[r]=ac[2][r]+tv2; v3[r]=ac[3][r]+tv3;
      ssq[r] = v0[r]*v0[r] + v1[r]*v1[r] + v2[r]*v2[r] + v3[r]*v3[r];
    }
#pragma unroll
    for (int off=1; off<32; off<<=1)
#pragma unroll
      for (int r=0;r<16;++r) ssq[r] += __shfl_xor(ssq[r], off, 64);
    if (l < 16) {
      int r = l;
      int grow = rw + (r&3) + 8*(r>>2) + 4*h;
      ynf[(r&3) + 8*(r>>2) + 4*h] = (grow >= 8191) ? -1.0e4f : KNEG * ssq[r];
    }
#pragma unroll
    for (int r=0;r<16;++r) {
      int rloc = (r&3) + 8*(r>>2) + 4*h;
      ytt[rloc*132 +   0 + l] = f2bf(KA2C * v0[r]);
      ytt[rloc*132 +  32 + l] = f2bf(KA2C * v1[r]);
      ytt[rloc*132 +  64 + l] = f2bf(KA2C * v2[r]);
      ytt[rloc*132 +  96 + l] = f2bf(KA2C * v3[r]);
    }
    __syncthreads();
    char* base = (char*)ctp + (size_t)T*T_STRIDE;
#pragma unroll
    for (int kc=0;kc<8;++kc) {
      const unsigned short* s = &ytt[l*132 + kc*16 + 8*h];
      uint2 a = *(const uint2*)(s);
      uint2 b = *(const uint2*)(s + 4);
      uint4 o; o.x=a.x; o.y=a.y; o.z=b.x; o.w=b.y;
      *(uint4*)(base + (jcw*9 + kc)*1024 + ln*16) = o;
    }
    {  // kc=8 slot: k=128 -> yn_hi, k=129 -> yn_lo (h=0 lanes only)
      float yn = ynf[l];
      unsigned short hi = f2bf(yn);
      float hif = __builtin_bit_cast(float, (unsigned)hi << 16);
      unsigned short lo = f2bf(yn - hif);
      uint4 o; o.x = (h == 0) ? ((unsigned)hi | ((unsigned)lo << 16)) : 0u;
      o.y = 0u; o.z = 0u; o.w = 0u;
      *(uint4*)(base + (jcw*9 + 8)*1024 + ln*16) = o;
    }
  } else {
    // ---- V task: 32 X1-rows; tile T2=(task-256)>>1, half=(task-256)&1 ----
    unsigned short* xs = (unsigned short*)slice;         // [32][136] bf16 = 8704 B
    const int tv_ = task - 256;
    const int T2 = tv_ >> 1, half = tv_ & 1;
    const int xr0 = T2*64 + half*32 + 1;
    {
      int rl = ln >> 1, ch2 = ln & 1;
      int row = xr0 + rl; if (row > 8191) row = 8191;   // pad j has g=0
      const float* src = X + (size_t)row*128 + ch2*64;
      unsigned short* dst = xs + rl*136 + ch2*64;
#pragma unroll
      for (int i=0;i<8;++i) {
        float4 p0 = *(const float4*)(src + i*8);
        float4 p1 = *(const float4*)(src + i*8 + 4);
        uint4 w;
        w.x = pk2bf(p0.x, p0.y); w.y = pk2bf(p0.z, p0.w);
        w.z = pk2bf(p1.x, p1.y); w.w = pk2bf(p1.z, p1.w);
        *(uint4*)(dst + i*8) = w;
      }
    }
    __syncthreads();
    char* base = (char*)ctp + (size_t)T2*T_STRIDE + V_OFF;
#pragma unroll
    for (int ch=0; ch<8; ++ch) {
      int jcl = ch >> 2, cc = ch & 3;
      int lr0 = jcl*16 + 8*h;
      int c = cc*32 + l;
      uint4 o;
      o.x = (unsigned)xs[(lr0+0)*136 + c] | ((unsigned)xs[(lr0+1)*136 + c] << 16);
      o.y = (unsigned)xs[(lr0+2)*136 + c] | ((unsigned)xs[(lr0+3)*136 + c] << 16);
      o.z = (unsigned)xs[(lr0+4)*136 + c] | ((unsigned)xs[(lr0+5)*136 + c] << 16);
      o.w = (unsigned)xs[(lr0+6)*136 + c] | ((unsigned)xs[(lr0+7)*136 + c] << 16);
      int jc16 = half*2 + jcl;
      *(uint4*)(base + (jc16*4 + cc)*1024 + ln*16) = o;
    }
  }
}

// ---------------- K_main (round-7: M=64/wave, 2 blocks/CU) ----------------
// grid (32, js); block 256 = 4 waves x 64 query rows (BM=256).
__global__ __launch_bounds__(256, 2) void k_main(
    const float* __restrict__ X,
    const unsigned short* __restrict__ ctp,
    float* __restrict__ accp,
    float* __restrict__ rsp,
    int js) {
  __shared__ unsigned short stg[T_STRIDE/2];   // 34816 B: yt(2jc x 9kc) + V
  const int tid = threadIdx.x;
  const int wv = tid >> 6, ln = tid & 63;
  const int l = ln & 31, h = ln >> 5;
  const int rowA = blockIdx.x*256 + wv*64 + l;  // qset A row, < 8192
  const int rowB = rowA + 32;                   // qset B row, < 8192

  bf16x8 qfA[8], qfB[8], qf8;  // Q as B-operand; qf8 = shared ones slot
  {
    const float* xa = X + (size_t)rowA * 128;
    const float* xb = X + (size_t)rowB * 128;
#pragma unroll
    for (int kc=0;kc<8;++kc) {
      float4 a0 = *(const float4*)(xa + kc*16 + 8*h);
      float4 a1 = *(const float4*)(xa + kc*16 + 8*h + 4);
      qfA[kc] = pack8(a0, a1);
      float4 b0 = *(const float4*)(xb + kc*16 + 8*h);
      float4 b1 = *(const float4*)(xb + kc*16 + 8*h + 4);
      qfB[kc] = pack8(b0, b1);
    }
    uint4 o; o.x = (h == 0) ? 0x3F803F80u : 0u; o.y = 0u; o.z = 0u; o.w = 0u;
    qf8 = __builtin_bit_cast(bf16x8, o);
  }
  f32x16 accA[4], accB[4];
#pragma unroll
  for (int cc=0;cc<4;++cc)
#pragma unroll
    for (int i=0;i<16;++i) { accA[cc][i]=0.f; accB[cc][i]=0.f; }
  float rsA = 0.f, rsB = 0.f;
  const int sp = blockIdx.y;
  const int Tbeg = (sp * 128) / js;
  const int Tend = ((sp + 1) * 128) / js;

  // softmax-exp of one S quadrant -> packed bf16 pair words
  auto dosm = [&](const f32x16& sa, unsigned wx[4], unsigned wy[4], float& rs) {
#pragma unroll
    for (int rg=0; rg<4; ++rg) {
      float g0 = fast_exp2(sa[rg*4+0]);
      float g1 = fast_exp2(sa[rg*4+1]);
      float g2 = fast_exp2(sa[rg*4+2]);
      float g3 = fast_exp2(sa[rg*4+3]);
      rs += (g0+g1) + (g2+g3);
      wx[rg] = pk2bf(g0, g1);
      wy[rg] = pk2bf(g2, g3);
    }
  };
  // S for one jc half: 9 A-chunk reads, each feeding both qsets (18 MFMA).
  auto doS = [&](int jc, f32x16& sA, f32x16& sB) {
#pragma unroll
    for (int i=0;i<16;++i) { sA[i]=0.f; sB[i]=0.f; }
#pragma unroll
    for (int kc=0;kc<8;++kc) {
      bf16x8 a = *(const bf16x8*)((const char*)stg + (jc*9+kc)*1024 + ln*16);
      sA = mfma_32x32x16(a, qfA[kc], sA);
      sB = mfma_32x32x16(a, qfB[kc], sB);
    }
    bf16x8 a = *(const bf16x8*)((const char*)stg + (jc*9+8)*1024 + ln*16);
    sA = mfma_32x32x16(a, qf8, sA);
    sB = mfma_32x32x16(a, qf8, sB);
  };
  // PV for one jc (jcb = 2*jc): each V-chunk read feeds both qsets.
  auto dopv = [&](int jcb, unsigned wxA[4], unsigned wyA[4],
                           unsigned wxB[4], unsigned wyB[4]) {
#pragma unroll
    for (int jj=0; jj<2; ++jj) {
      unsigned axA = wxA[2*jj], bxA = wxA[2*jj+1];
      unsigned ayA = wyA[2*jj], byA = wyA[2*jj+1];
      pl32swap(axA, bxA);
      pl32swap(ayA, byA);
      uint4 gvA; gvA.x = axA; gvA.y = ayA; gvA.z = bxA; gvA.w = byA;
      bf16x8 pbA = __builtin_bit_cast(bf16x8, gvA);
      unsigned axB = wxB[2*jj], bxB = wxB[2*jj+1];
      unsigned ayB = wyB[2*jj], byB = wyB[2*jj+1];
      pl32swap(axB, bxB);
      pl32swap(ayB, byB);
      uint4 gvB; gvB.x = axB; gvB.y = ayB; gvB.z = bxB; gvB.w = byB;
      bf16x8 pbB = __builtin_bit_cast(bf16x8, gvB);
#pragma unroll
      for (int cc=0;cc<4;++cc) {
        bf16x8 a2 = *(const bf16x8*)((const char*)stg + V_OFF + ((jcb+jj)*4+cc)*1024 + ln*16);
        accA[cc] = mfma_32x32x16(a2, pbA, accA[cc]);
        accB[cc] = mfma_32x32x16(a2, pbB, accB[cc]);
      }
    }
  };

  // prologue: stage full tile Tbeg (34 chunks of 1 KB)
  {
    const char* cb = (const char*)ctp + (size_t)Tbeg*T_STRIDE;
#pragma unroll
    for (int i=0;i<9;++i) {
      int c = wv + 4*i;
      if (c < 34) gl2lds16(cb + c*1024 + ln*16, (char*)stg + c*1024);
    }
  }
  __syncthreads();  // drain prologue stage

  for (int T = Tbeg; T < Tend; ++T) {
    const bool pf = (T+1 < Tend);
    const char* nb = (const char*)ctp + (size_t)(T+1)*T_STRIDE;

    f32x16 sA, sB;
    unsigned wxA[4], wyA[4], wxB[4], wyB[4];
    // ---- jc=0: S, exp, PV (V jc16 0,1 = chunks 18..25) ----
    doS(0, sA, sB);
    dosm(sA, wxA, wyA, rsA);
    dosm(sB, wxB, wyB, rsB);
    dopv(0, wxA, wyA, wxB, wyB);
    // ---- jc=1: S, exp ----
    doS(1, sA, sB);
    dosm(sA, wxA, wyA, rsA);
    dosm(sB, wxB, wyB, rsB);

    __syncthreads();       // yt fully read (S1); V-lo read (PV0) block-wide
    if (pf) {              // stage next yt (0..17) + V-lo (18..25); drains at end BAR
#pragma unroll
      for (int i=0;i<7;++i) {
        int c = wv + 4*i;
        if (c < 26) gl2lds16(nb + c*1024 + ln*16, (char*)stg + c*1024);
      }
    }
    dopv(2, wxA, wyA, wxB, wyB);   // PV jc=1 (V-hi chunks 26..33)

    __syncthreads();       // V-hi read done; yt+V-lo stage drained (vmcnt 0)
    if (pf) {              // stage next V-hi (26..33); drains at next mid BAR
#pragma unroll
      for (int i=0;i<2;++i) {
        int c = 26 + wv + 4*i;
        gl2lds16(nb + c*1024 + ln*16, (char*)stg + c*1024);
      }
    }
  }
  rsA += __shfl_xor(rsA, 32, 64);
  rsB += __shfl_xor(rsB, 32, 64);
  if (h == 0) {
    rsp[(size_t)sp*8192 + rowA] = rsA;
    rsp[(size_t)sp*8192 + rowB] = rsB;
  }
  // acc^T: lane holds out^T[c = cc*32+(r&3)+8(r>>2)+4h][m = row]; store [sp][c][row]
#pragma unroll
  for (int cc=0;cc<4;++cc)
#pragma unroll
    for (int r=0;r<16;++r) {
      int c = cc*32 + (r&3) + 8*(r>>2) + 4*h;
      accp[((size_t)sp*128 + c)*8192 + rowA] = accA[cc][r];
      accp[((size_t)sp*128 + c)*8192 + rowB] = accB[cc][r];
    }
}

// ---------------- K_fin: pipelined split-reduce + normalize + transpose --------
// grid (128, 4) = 512 blocks (2/CU). Block: 64 rows x 32 cols.
// Thread: rows rq*4..+3 (r-contig float4), cols c0 + cg*2..+1. sp-loop unroll 4
// -> 8 float4 loads in flight per thread.
__global__ __launch_bounds__(256) void k_fin(const float* __restrict__ accp,
                                             const float* __restrict__ rsp,
                                             float* __restrict__ out,
                                             int js) {
  __shared__ float tr[64*36];   // stride 36 floats (144 B, 16B-aligned rows)
  __shared__ float rinv[64];
  const int tid = threadIdx.x;
  const int r0 = blockIdx.x * 64;
  const int c0 = blockIdx.y * 32;
  if (tid < 64) {
    float s = 0.f;
    for (int sp=0; sp<js; ++sp) s += rsp[(size_t)sp*8192 + r0 + tid];
    rinv[tid] = 1.f / s;
  }
  const int rq = tid & 15, cg = tid >> 4;   // rows rq*4..+3, cols c0+cg*2..+1
  float v[2][4];
#pragma unroll
  for (int cc=0;cc<2;++cc)
#pragma unroll
    for (int k=0;k<4;++k) v[cc][k]=0.f;
#pragma unroll 4
  for (int sp=0; sp<js; ++sp) {
    const float* base = accp + ((size_t)sp*128 + c0 + cg*2)*8192 + r0 + rq*4;
    float4 p0 = *(const float4*)(base);
    float4 p1 = *(const float4*)(base + 8192);
    v[0][0]+=p0.x; v[0][1]+=p0.y; v[0][2]+=p0.z; v[0][3]+=p0.w;
    v[1][0]+=p1.x; v[1][1]+=p1.y; v[1][2]+=p1.z; v[1][3]+=p1.w;
  }
  __syncthreads();
#pragma unroll
  for (int cc=0;cc<2;++cc)
#pragma unroll
    for (int k=0;k<4;++k)
      tr[(rq*4+k)*36 + cg*2+cc] = v[cc][k] * rinv[rq*4+k];
  __syncthreads();
  {
    int r = tid >> 2, q = tid & 3;   // 64 rows x 4 col-groups of 8
    int grow = r0 + r;
    if (grow < 8191) {
      float* dst = out + (size_t)grow*128 + c0 + q*8;
      const float* s2 = &tr[r*36 + q*8];
      *(float4*)(dst)     = *(const float4*)(s2);
      *(float4*)(dst + 4) = *(const float4*)(s2 + 4);
    }
  }
}

extern "C" void kernel_launch(void* const* d_in, const int* in_sizes, int n_in,
                              void* d_out, int out_size, void* d_ws, size_t ws_size,
                              hipStream_t stream) {
  const float* X = (const float*)d_in[0];
  const float* y = (const float*)d_in[1];
  // d_in[2] = y_next (unused by reference)
  const float* R = (const float*)d_in[3];
  const float* t = (const float*)d_in[4];
  float* out = (float*)d_out;
  char* ws = (char*)d_ws;

  unsigned short* ctp = (unsigned short*)ws;                 // 128 * 34816 = 4.456 MB
  size_t rspoff = (size_t)128 * T_STRIDE;
  float* rsp  = (float*)(ws + rspoff);                       // js*32 KB
  size_t accoff = rspoff + 512*1024;
  float* accp = (float*)(ws + accoff);                       // js * 4 MB

  int js = 16;  // 32 x 16 = 512 blocks = exactly 2 blocks/CU
  while (js > 1 && accoff + (size_t)js*128*8192*4 > ws_size) js >>= 1;

  k_prep<<<dim3(512), dim3(64), 0, stream>>>(y, R, t, X, ctp);
  k_main<<<dim3(32, js), dim3(256), 0, stream>>>(X, ctp, accp, rsp, js);
  k_fin<<<dim3(128, 4), dim3(256), 0, stream>>>(accp, rsp, out, js);
}

// Round 3
// 142.371 us; speedup vs baseline: 1.5274x; 1.5274x over previous
//
#include <hip/hip_runtime.h>
#include <hip/hip_bf16.h>

// Gaussian-kernel regression, fused flash-attention style. 3-kernel structure.
// K_prep: 512 one-wave blocks: 256x yt=y@R^T+t GEMM -> KA2C*yt perm + yn hi/lo
//   folded into K=144 slot; 256x V=X[1:] transpose perm.
// K_main (round-8): round-6 base (permlane P + split-stage pipeline; proven
//   129.4 total) + dep-chain split: each S quadrant = 2 independent partial
//   MFMA chains (5+4) merged by v_add -> dependency wall halved; exp0 hoisted
//   between S0/S1 (fills MFMA shadow, keeps reg peak ~168 <= 3-wave budget);
//   setprio(1) around MFMA clusters (3 independent blocks/CU -> arbitrage).
// NOTE (R7, this session): M=64/wave needs ~270 regs vs 256 budget -> scratch
//   spill storm (FETCH 19.5->217 MB, k_main 44->134us). Never exceed the
//   3-wave=170 / 2-wave=256 unified VGPR+AGPR budget.
// K_fin : grid (128,4)=512 blocks, sp-loop unrolled x4 -> pipelined 48MB read.
// NOTE (R9, prior session): grid-wide barriers w/ agent-scope fences on gfx950
// = L2 writeback storms, 12x slowdown. Never again.

#define LOG2E 1.44269504088896340736f
#define KNEG (-(1.0f/256.0f)*LOG2E)
#define KA2C (2.0f*(1.0f/256.0f)*LOG2E)

typedef __attribute__((ext_vector_type(4)))  float f32x4;
typedef __attribute__((ext_vector_type(16))) float f32x16;
typedef __attribute__((ext_vector_type(8)))  short bf16x8;

__device__ __forceinline__ unsigned short f2bf(float f) {
  unsigned u = __builtin_bit_cast(unsigned, f);
  u = (u + 0x7fffu + ((u >> 16) & 1u)) >> 16;  // RNE; inputs finite
  return (unsigned short)u;
}
__device__ __forceinline__ unsigned pk2bf(float a, float b) {
  __hip_bfloat162 h = __float22bfloat162_rn(float2{a, b});  // v_cvt_pk_bf16_f32
  unsigned u;
  __builtin_memcpy(&u, &h, 4);
  return u;
}
__device__ __forceinline__ bf16x8 pack8(float4 p0, float4 p1) {
  uint4 u;
  u.x = pk2bf(p0.x, p0.y); u.y = pk2bf(p0.z, p0.w);
  u.z = pk2bf(p1.x, p1.y); u.w = pk2bf(p1.z, p1.w);
  return __builtin_bit_cast(bf16x8, u);
}
__device__ __forceinline__ float fast_exp2(float x) {
#if __has_builtin(__builtin_amdgcn_exp2f)
  return __builtin_amdgcn_exp2f(x);
#else
  return exp2f(x);
#endif
}
__device__ __forceinline__ void gl2lds16(const void* g, void* l) {
  __builtin_amdgcn_global_load_lds((const __attribute__((address_space(1))) unsigned int*)g,
                                   (__attribute__((address_space(3))) unsigned int*)l, 16, 0, 0);
}
__device__ __forceinline__ f32x16 mfma_32x32x16(bf16x8 a, bf16x8 b, f32x16 c) {
  return __builtin_amdgcn_mfma_f32_32x32x16_bf16(a, b, c, 0, 0, 0);
}
// Exchanges a's high 32 lanes with b's low 32 lanes (gfx950 permlane32_swap).
__device__ __forceinline__ void pl32swap(unsigned &a, unsigned &b) {
#if __has_builtin(__builtin_amdgcn_permlane32_swap)
  auto r = __builtin_amdgcn_permlane32_swap((int)a, (int)b, false, false);
  a = (unsigned)r[0];
  b = (unsigned)r[1];
#else
  unsigned pa = (unsigned)__shfl_xor((int)a, 32, 64);
  unsigned pb = (unsigned)__shfl_xor((int)b, 32, 64);
  bool hi = (threadIdx.x & 32) != 0;
  unsigned na = hi ? pb : a;
  unsigned nb = hi ? b  : pa;
  a = na; b = nb;
#endif
}

#define T_STRIDE 34816   // per-64j-tile bytes: 2 jc x 9 kc x 1024 (yt) + 16384 (V)
#define V_OFF    18432

// ---------------- K_prep: 512 one-wave blocks ----------------
// task = blockIdx.x. task<256: yt GEMM for 32 rows (tile task>>1, half task&1).
// task>=256: V transpose for 32 X1-rows.
__global__ __launch_bounds__(64) void k_prep(const float* __restrict__ y,
                                             const float* __restrict__ R,
                                             const float* __restrict__ t,
                                             const float* __restrict__ X,
                                             unsigned short* __restrict__ ctp) {
  __shared__ char slice[8704];
  const int task = blockIdx.x;
  const int ln = threadIdx.x;
  const int l = ln & 31, h = ln >> 5;

  if (task < 256) {
    // ---- yt task: rows rw..rw+31; tile T=task>>1, jc half jcw=task&1 ----
    unsigned short* ytt = (unsigned short*)slice;        // [32][132] = 8448 B
    float* ynf = (float*)(slice + 8448);                 // 32 floats
    const int T = task >> 1, jcw = task & 1;
    const int rw = task * 32;
    bf16x8 af[8];
    {
      int row = rw + l; if (row > 8190) row = 8190;
      const float* yr = y + (size_t)row * 128;
#pragma unroll
      for (int kc = 0; kc < 8; ++kc) {
        float4 p0 = *(const float4*)(yr + kc*16 + 8*h);
        float4 p1 = *(const float4*)(yr + kc*16 + 8*h + 4);
        af[kc] = pack8(p0, p1);
      }
    }
    f32x16 ac[4];
#pragma unroll
    for (int cc=0; cc<4; ++cc)
#pragma unroll
      for (int i=0;i<16;++i) ac[cc][i] = 0.f;
#pragma unroll
    for (int cc=0; cc<4; ++cc) {
      const float* Rr = R + (size_t)(cc*32 + l) * 128;   // R^T[k][c] = R[c][k]
#pragma unroll
      for (int kc=0; kc<8; ++kc) {
        float4 p0 = *(const float4*)(Rr + kc*16 + 8*h);
        float4 p1 = *(const float4*)(Rr + kc*16 + 8*h + 4);
        ac[cc] = mfma_32x32x16(af[kc], pack8(p0, p1), ac[cc]);
      }
    }
    // D: lane holds yt[rw + (r&3)+8*(r>>2)+4h][cc*32 + l]
    float tv0 = t[l], tv1 = t[32+l], tv2 = t[64+l], tv3 = t[96+l];
    float v0[16], v1[16], v2[16], v3[16], ssq[16];
#pragma unroll
    for (int r=0;r<16;++r) {
      v0[r]=ac[0][r]+tv0; v1[r]=ac[1][r]+tv1; v2[r]=ac[2][r]+tv2; v3[r]=ac[3][r]+tv3;
      ssq[r] = v0[r]*v0[r] + v1[r]*v1[r] + v2[r]*v2[r] + v3[r]*v3[r];
    }
#pragma unroll
    for (int off=1; off<32; off<<=1)
#pragma unroll
      for (int r=0;r<16;++r) ssq[r] += __shfl_xor(ssq[r], off, 64);
    if (l < 16) {
      int r = l;
      int grow = rw + (r&3) + 8*(r>>2) + 4*h;
      ynf[(r&3) + 8*(r>>2) + 4*h] = (grow >= 8191) ? -1.0e4f : KNEG * ssq[r];
    }
#pragma unroll
    for (int r=0;r<16;++r) {
      int rloc = (r&3) + 8*(r>>2) + 4*h;
      ytt[rloc*132 +   0 + l] = f2bf(KA2C * v0[r]);
      ytt[rloc*132 +  32 + l] = f2bf(KA2C * v1[r]);
      ytt[rloc*132 +  64 + l] = f2bf(KA2C * v2[r]);
      ytt[rloc*132 +  96 + l] = f2bf(KA2C * v3[r]);
    }
    __syncthreads();
    char* base = (char*)ctp + (size_t)T*T_STRIDE;
#pragma unroll
    for (int kc=0;kc<8;++kc) {
      const unsigned short* s = &ytt[l*132 + kc*16 + 8*h];
      uint2 a = *(const uint2*)(s);
      uint2 b = *(const uint2*)(s + 4);
      uint4 o; o.x=a.x; o.y=a.y; o.z=b.x; o.w=b.y;
      *(uint4*)(base + (jcw*9 + kc)*1024 + ln*16) = o;
    }
    {  // kc=8 slot: k=128 -> yn_hi, k=129 -> yn_lo (h=0 lanes only)
      float yn = ynf[l];
      unsigned short hi = f2bf(yn);
      float hif = __builtin_bit_cast(float, (unsigned)hi << 16);
      unsigned short lo = f2bf(yn - hif);
      uint4 o; o.x = (h == 0) ? ((unsigned)hi | ((unsigned)lo << 16)) : 0u;
      o.y = 0u; o.z = 0u; o.w = 0u;
      *(uint4*)(base + (jcw*9 + 8)*1024 + ln*16) = o;
    }
  } else {
    // ---- V task: 32 X1-rows; tile T2=(task-256)>>1, half=(task-256)&1 ----
    unsigned short* xs = (unsigned short*)slice;         // [32][136] bf16 = 8704 B
    const int tv_ = task - 256;
    const int T2 = tv_ >> 1, half = tv_ & 1;
    const int xr0 = T2*64 + half*32 + 1;
    {
      int rl = ln >> 1, ch2 = ln & 1;
      int row = xr0 + rl; if (row > 8191) row = 8191;   // pad j has g=0
      const float* src = X + (size_t)row*128 + ch2*64;
      unsigned short* dst = xs + rl*136 + ch2*64;
#pragma unroll
      for (int i=0;i<8;++i) {
        float4 p0 = *(const float4*)(src + i*8);
        float4 p1 = *(const float4*)(src + i*8 + 4);
        uint4 w;
        w.x = pk2bf(p0.x, p0.y); w.y = pk2bf(p0.z, p0.w);
        w.z = pk2bf(p1.x, p1.y); w.w = pk2bf(p1.z, p1.w);
        *(uint4*)(dst + i*8) = w;
      }
    }
    __syncthreads();
    char* base = (char*)ctp + (size_t)T2*T_STRIDE + V_OFF;
#pragma unroll
    for (int ch=0; ch<8; ++ch) {
      int jcl = ch >> 2, cc = ch & 3;
      int lr0 = jcl*16 + 8*h;
      int c = cc*32 + l;
      uint4 o;
      o.x = (unsigned)xs[(lr0+0)*136 + c] | ((unsigned)xs[(lr0+1)*136 + c] << 16);
      o.y = (unsigned)xs[(lr0+2)*136 + c] | ((unsigned)xs[(lr0+3)*136 + c] << 16);
      o.z = (unsigned)xs[(lr0+4)*136 + c] | ((unsigned)xs[(lr0+5)*136 + c] << 16);
      o.w = (unsigned)xs[(lr0+6)*136 + c] | ((unsigned)xs[(lr0+7)*136 + c] << 16);
      int jc16 = half*2 + jcl;
      *(uint4*)(base + (jc16*4 + cc)*1024 + ln*16) = o;
    }
  }
}

// ---------------- K_main (round-8: chain-split + setprio) ----------------
// grid (64, js); block 256 = 4 waves x 32 query rows (BM=128); 3 blocks/CU.
// Per tile: S0(2-chain) exp0 S1(2-chain) | BAR | stage yt | exp1 PV0 PV1 |
// BAR | stage V.  Hazards identical to round-6 (yt read only pre-BAR1; V-lo
// by PV0, V-hi by PV1 pre-BAR2; every stage drains at the following barrier).
__global__ __launch_bounds__(256, 3) void k_main(
    const float* __restrict__ X,
    const unsigned short* __restrict__ ctp,
    float* __restrict__ accp,
    float* __restrict__ rsp,
    int js) {
  __shared__ unsigned short stg[T_STRIDE/2];   // 34816 B: yt(2jc x 9kc) + V
  const int tid = threadIdx.x;
  const int wv = tid >> 6, ln = tid & 63;
  const int l = ln & 31, h = ln >> 5;
  const int row = blockIdx.x*128 + wv*32 + l;  // query row, always < 8192

  bf16x8 qf[9];  // Q as B-operand: x[row][k], plus k=128,129 -> 1,1 (h=0)
  {
    const float* xr = X + (size_t)row * 128;
#pragma unroll
    for (int kc=0;kc<8;++kc) {
      float4 p0 = *(const float4*)(xr + kc*16 + 8*h);
      float4 p1 = *(const float4*)(xr + kc*16 + 8*h + 4);
      qf[kc] = pack8(p0, p1);
    }
    uint4 o; o.x = (h == 0) ? 0x3F803F80u : 0u; o.y = 0u; o.z = 0u; o.w = 0u;
    qf[8] = __builtin_bit_cast(bf16x8, o);
  }
  f32x16 acc[4];
#pragma unroll
  for (int cc=0;cc<4;++cc)
#pragma unroll
    for (int i=0;i<16;++i) acc[cc][i]=0.f;
  float rs = 0.f;
  const int sp = blockIdx.y;
  const int Tbeg = (sp * 128) / js;
  const int Tend = ((sp + 1) * 128) / js;

  // softmax-exp of one S quadrant -> packed bf16 pair words
  auto dosm = [&](const f32x16& sa, unsigned wx[4], unsigned wy[4]) {
#pragma unroll
    for (int rg=0; rg<4; ++rg) {
      float g0 = fast_exp2(sa[rg*4+0]);
      float g1 = fast_exp2(sa[rg*4+1]);
      float g2 = fast_exp2(sa[rg*4+2]);
      float g3 = fast_exp2(sa[rg*4+3]);
      rs += (g0+g1) + (g2+g3);
      wx[rg] = pk2bf(g0, g1);
      wy[rg] = pk2bf(g2, g3);
    }
  };
  // S quadrant jc: two independent partial MFMA chains (even/odd kc), merged.
  // Halves the 9-deep dependent-MFMA wall that dominated round-6's idle.
  auto doS = [&](int jc) -> f32x16 {
    f32x16 pe, po;
#pragma unroll
    for (int i=0;i<16;++i) { pe[i]=0.f; po[i]=0.f; }
    __builtin_amdgcn_s_setprio(1);
#pragma unroll
    for (int kc=0;kc<8;kc+=2) {
      bf16x8 a0 = *(const bf16x8*)((const char*)stg + (jc*9+kc)*1024 + ln*16);
      pe = mfma_32x32x16(a0, qf[kc], pe);
      bf16x8 a1 = *(const bf16x8*)((const char*)stg + (jc*9+kc+1)*1024 + ln*16);
      po = mfma_32x32x16(a1, qf[kc+1], po);
    }
    {
      bf16x8 a8 = *(const bf16x8*)((const char*)stg + (jc*9+8)*1024 + ln*16);
      pe = mfma_32x32x16(a8, qf[8], pe);
    }
    __builtin_amdgcn_s_setprio(0);
    f32x16 s;
#pragma unroll
    for (int i=0;i<16;++i) s[i] = pe[i] + po[i];
    return s;
  };
  // PV for one jc: permlane32_swap redistributes packed P words in-register.
  auto dopv = [&](int jcb, unsigned wx[4], unsigned wy[4]) {
#pragma unroll
    for (int jj=0; jj<2; ++jj) {
      unsigned ax = wx[2*jj], bx = wx[2*jj+1];
      unsigned ay = wy[2*jj], by = wy[2*jj+1];
      pl32swap(ax, bx);
      pl32swap(ay, by);
      uint4 gv; gv.x = ax; gv.y = ay; gv.z = bx; gv.w = by;
      bf16x8 pb = __builtin_bit_cast(bf16x8, gv);
      __builtin_amdgcn_s_setprio(1);
#pragma unroll
      for (int cc=0;cc<4;++cc) {
        bf16x8 a2 = *(const bf16x8*)((const char*)stg + V_OFF + ((jcb+jj)*4+cc)*1024 + ln*16);
        acc[cc] = mfma_32x32x16(a2, pb, acc[cc]);
      }
      __builtin_amdgcn_s_setprio(0);
    }
  };

  // prologue: stage full tile Tbeg (34 chunks of 1 KB)
  {
    const char* cb = (const char*)ctp + (size_t)Tbeg*T_STRIDE;
#pragma unroll
    for (int i=0;i<9;++i) {
      int c = wv + 4*i;
      if (c < 34) gl2lds16(cb + c*1024 + ln*16, (char*)stg + c*1024);
    }
  }
  __syncthreads();  // drain prologue stage

  for (int T = Tbeg; T < Tend; ++T) {
    const bool pf = (T+1 < Tend);
    const char* nb = (const char*)ctp + (size_t)(T+1)*T_STRIDE;

    unsigned wx0[4], wy0[4], wx1[4], wy1[4];
    f32x16 sa0 = doS(0);
    dosm(sa0, wx0, wy0);   // exp0 between quadrants: sa0 dead before S1 partials
    f32x16 sa1 = doS(1);

    __syncthreads();       // all waves done reading yt region
    if (pf) {              // prefetch next yt (chunks 0..17); drains at end BAR
#pragma unroll
      for (int i=0;i<5;++i) {
        int c = wv + 4*i;
        if (c < 18) gl2lds16(nb + c*1024 + ln*16, (char*)stg + c*1024);
      }
    }
    dosm(sa1, wx1, wy1);
    dopv(0, wx0, wy0);     // PV jc=0: 8 MFMAs (V-lo)
    dopv(2, wx1, wy1);     // PV jc=1: 8 MFMAs (V-hi)

    __syncthreads();       // all V reads done; vmcnt(0) -> next yt landed
    if (pf) {              // stage next V (chunks 18..33); drains at mid BAR
#pragma unroll
      for (int i=0;i<4;++i) {
        int c = 18 + wv + 4*i;
        gl2lds16(nb + c*1024 + ln*16, (char*)stg + c*1024);
      }
    }
  }
  rs += __shfl_xor(rs, 32, 64);
  if (h == 0) rsp[(size_t)sp*8192 + row] = rs;
  // acc^T: lane holds out^T[c = cc*32+(r&3)+8(r>>2)+4h][m = row]; store [sp][c][row]
#pragma unroll
  for (int cc=0;cc<4;++cc)
#pragma unroll
    for (int r=0;r<16;++r) {
      int c = cc*32 + (r&3) + 8*(r>>2) + 4*h;
      accp[((size_t)sp*128 + c)*8192 + row] = acc[cc][r];
    }
}

// ---------------- K_fin: pipelined split-reduce + normalize + transpose --------
// grid (128, 4) = 512 blocks (2/CU). Block: 64 rows x 32 cols.
// Thread: rows rq*4..+3 (r-contig float4), cols c0 + cg*2..+1. sp-loop unroll 4
// -> 8 float4 loads in flight per thread.
__global__ __launch_bounds__(256) void k_fin(const float* __restrict__ accp,
                                             const float* __restrict__ rsp,
                                             float* __restrict__ out,
                                             int js) {
  __shared__ float tr[64*36];   // stride 36 floats (144 B, 16B-aligned rows)
  __shared__ float rinv[64];
  const int tid = threadIdx.x;
  const int r0 = blockIdx.x * 64;
  const int c0 = blockIdx.y * 32;
  if (tid < 64) {
    float s = 0.f;
    for (int sp=0; sp<js; ++sp) s += rsp[(size_t)sp*8192 + r0 + tid];
    rinv[tid] = 1.f / s;
  }
  const int rq = tid & 15, cg = tid >> 4;   // rows rq*4..+3, cols c0+cg*2..+1
  float v[2][4];
#pragma unroll
  for (int cc=0;cc<2;++cc)
#pragma unroll
    for (int k=0;k<4;++k) v[cc][k]=0.f;
#pragma unroll 4
  for (int sp=0; sp<js; ++sp) {
    const float* base = accp + ((size_t)sp*128 + c0 + cg*2)*8192 + r0 + rq*4;
    float4 p0 = *(const float4*)(base);
    float4 p1 = *(const float4*)(base + 8192);
    v[0][0]+=p0.x; v[0][1]+=p0.y; v[0][2]+=p0.z; v[0][3]+=p0.w;
    v[1][0]+=p1.x; v[1][1]+=p1.y; v[1][2]+=p1.z; v[1][3]+=p1.w;
  }
  __syncthreads();
#pragma unroll
  for (int cc=0;cc<2;++cc)
#pragma unroll
    for (int k=0;k<4;++k)
      tr[(rq*4+k)*36 + cg*2+cc] = v[cc][k] * rinv[rq*4+k];
  __syncthreads();
  {
    int r = tid >> 2, q = tid & 3;   // 64 rows x 4 col-groups of 8
    int grow = r0 + r;
    if (grow < 8191) {
      float* dst = out + (size_t)grow*128 + c0 + q*8;
      const float* s2 = &tr[r*36 + q*8];
      *(float4*)(dst)     = *(const float4*)(s2);
      *(float4*)(dst + 4) = *(const float4*)(s2 + 4);
    }
  }
}

extern "C" void kernel_launch(void* const* d_in, const int* in_sizes, int n_in,
                              void* d_out, int out_size, void* d_ws, size_t ws_size,
                              hipStream_t stream) {
  const float* X = (const float*)d_in[0];
  const float* y = (const float*)d_in[1];
  // d_in[2] = y_next (unused by reference)
  const float* R = (const float*)d_in[3];
  const float* t = (const float*)d_in[4];
  float* out = (float*)d_out;
  char* ws = (char*)d_ws;

  unsigned short* ctp = (unsigned short*)ws;                 // 128 * 34816 = 4.456 MB
  size_t rspoff = (size_t)128 * T_STRIDE;
  float* rsp  = (float*)(ws + rspoff);                       // js*32 KB
  size_t accoff = rspoff + 512*1024;
  float* accp = (float*)(ws + accoff);                       // js * 4 MB

  int js = 12;  // 64 x 12 = 768 blocks = exactly 3 blocks/CU
  while (js > 1 && accoff + (size_t)js*128*8192*4 > ws_size) js >>= 1;

  k_prep<<<dim3(512), dim3(64), 0, stream>>>(y, R, t, X, ctp);
  k_main<<<dim3(64, js), dim3(256), 0, stream>>>(X, ctp, accp, rsp, js);
  k_fin<<<dim3(128, 4), dim3(256), 0, stream>>>(accp, rsp, out, js);
}

// Round 4
// 130.638 us; speedup vs baseline: 1.6646x; 1.0898x over previous
//
#include <hip/hip_runtime.h>
#include <hip/hip_bf16.h>

// Gaussian-kernel regression, fused flash-attention style. 3-kernel structure.
// K_prep: 512 one-wave blocks: 256x yt=y@R^T+t GEMM -> KA2C*yt perm + yn hi/lo
//   folded into K=144 slot; 256x V=X[1:] transpose perm.
// K_main (round-9): round-6 compute (permlane P, proven) + FULL LDS double
//   buffer (2x34816=69632B, 2 blocks/CU) + ONE barrier per tile: the entire
//   next-tile stage (34 chunks) is issued at tile start into the other buffer
//   and drains at the end-of-tile barrier, covered by the whole tile's
//   compute (S+exp+PV ~1100cyc vs ~330cyc stage). js=8 -> 512 blocks = 2/CU
//   exact, and split-k traffic -16MB on both k_main writes and k_fin reads.
// NOTE (R7, this session): M=64/wave needs ~270 regs vs 256 budget -> scratch
//   spill storm (FETCH 19.5->217 MB, k_main 44->134us). Stay in reg budget.
// NOTE (R8, this session): chain-split S + setprio + exp-between-S regressed
//   k_main 44->59us (MfmaUtil down, +13MB write = localMem). Keep the R1/R6
//   compute body verbatim.
// K_fin : grid (128,4)=512 blocks, sp-loop unrolled x4 -> pipelined 32MB read.
// NOTE (R9, prior session): grid-wide barriers w/ agent-scope fences on gfx950
// = L2 writeback storms, 12x slowdown. Never again.

#define LOG2E 1.44269504088896340736f
#define KNEG (-(1.0f/256.0f)*LOG2E)
#define KA2C (2.0f*(1.0f/256.0f)*LOG2E)

typedef __attribute__((ext_vector_type(4)))  float f32x4;
typedef __attribute__((ext_vector_type(16))) float f32x16;
typedef __attribute__((ext_vector_type(8)))  short bf16x8;

__device__ __forceinline__ unsigned short f2bf(float f) {
  unsigned u = __builtin_bit_cast(unsigned, f);
  u = (u + 0x7fffu + ((u >> 16) & 1u)) >> 16;  // RNE; inputs finite
  return (unsigned short)u;
}
__device__ __forceinline__ unsigned pk2bf(float a, float b) {
  __hip_bfloat162 h = __float22bfloat162_rn(float2{a, b});  // v_cvt_pk_bf16_f32
  unsigned u;
  __builtin_memcpy(&u, &h, 4);
  return u;
}
__device__ __forceinline__ bf16x8 pack8(float4 p0, float4 p1) {
  uint4 u;
  u.x = pk2bf(p0.x, p0.y); u.y = pk2bf(p0.z, p0.w);
  u.z = pk2bf(p1.x, p1.y); u.w = pk2bf(p1.z, p1.w);
  return __builtin_bit_cast(bf16x8, u);
}
__device__ __forceinline__ float fast_exp2(float x) {
#if __has_builtin(__builtin_amdgcn_exp2f)
  return __builtin_amdgcn_exp2f(x);
#else
  return exp2f(x);
#endif
}
__device__ __forceinline__ void gl2lds16(const void* g, void* l) {
  __builtin_amdgcn_global_load_lds((const __attribute__((address_space(1))) unsigned int*)g,
                                   (__attribute__((address_space(3))) unsigned int*)l, 16, 0, 0);
}
__device__ __forceinline__ f32x16 mfma_32x32x16(bf16x8 a, bf16x8 b, f32x16 c) {
  return __builtin_amdgcn_mfma_f32_32x32x16_bf16(a, b, c, 0, 0, 0);
}
// Exchanges a's high 32 lanes with b's low 32 lanes (gfx950 permlane32_swap).
__device__ __forceinline__ void pl32swap(unsigned &a, unsigned &b) {
#if __has_builtin(__builtin_amdgcn_permlane32_swap)
  auto r = __builtin_amdgcn_permlane32_swap((int)a, (int)b, false, false);
  a = (unsigned)r[0];
  b = (unsigned)r[1];
#else
  unsigned pa = (unsigned)__shfl_xor((int)a, 32, 64);
  unsigned pb = (unsigned)__shfl_xor((int)b, 32, 64);
  bool hi = (threadIdx.x & 32) != 0;
  unsigned na = hi ? pb : a;
  unsigned nb = hi ? b  : pa;
  a = na; b = nb;
#endif
}

#define T_STRIDE 34816   // per-64j-tile bytes: 2 jc x 9 kc x 1024 (yt) + 16384 (V)
#define V_OFF    18432

// ---------------- K_prep: 512 one-wave blocks ----------------
// task = blockIdx.x. task<256: yt GEMM for 32 rows (tile task>>1, half task&1).
// task>=256: V transpose for 32 X1-rows.
__global__ __launch_bounds__(64) void k_prep(const float* __restrict__ y,
                                             const float* __restrict__ R,
                                             const float* __restrict__ t,
                                             const float* __restrict__ X,
                                             unsigned short* __restrict__ ctp) {
  __shared__ char slice[8704];
  const int task = blockIdx.x;
  const int ln = threadIdx.x;
  const int l = ln & 31, h = ln >> 5;

  if (task < 256) {
    // ---- yt task: rows rw..rw+31; tile T=task>>1, jc half jcw=task&1 ----
    unsigned short* ytt = (unsigned short*)slice;        // [32][132] = 8448 B
    float* ynf = (float*)(slice + 8448);                 // 32 floats
    const int T = task >> 1, jcw = task & 1;
    const int rw = task * 32;
    bf16x8 af[8];
    {
      int row = rw + l; if (row > 8190) row = 8190;
      const float* yr = y + (size_t)row * 128;
#pragma unroll
      for (int kc = 0; kc < 8; ++kc) {
        float4 p0 = *(const float4*)(yr + kc*16 + 8*h);
        float4 p1 = *(const float4*)(yr + kc*16 + 8*h + 4);
        af[kc] = pack8(p0, p1);
      }
    }
    f32x16 ac[4];
#pragma unroll
    for (int cc=0; cc<4; ++cc)
#pragma unroll
      for (int i=0;i<16;++i) ac[cc][i] = 0.f;
#pragma unroll
    for (int cc=0; cc<4; ++cc) {
      const float* Rr = R + (size_t)(cc*32 + l) * 128;   // R^T[k][c] = R[c][k]
#pragma unroll
      for (int kc=0; kc<8; ++kc) {
        float4 p0 = *(const float4*)(Rr + kc*16 + 8*h);
        float4 p1 = *(const float4*)(Rr + kc*16 + 8*h + 4);
        ac[cc] = mfma_32x32x16(af[kc], pack8(p0, p1), ac[cc]);
      }
    }
    // D: lane holds yt[rw + (r&3)+8*(r>>2)+4h][cc*32 + l]
    float tv0 = t[l], tv1 = t[32+l], tv2 = t[64+l], tv3 = t[96+l];
    float v0[16], v1[16], v2[16], v3[16], ssq[16];
#pragma unroll
    for (int r=0;r<16;++r) {
      v0[r]=ac[0][r]+tv0; v1[r]=ac[1][r]+tv1; v2[r]=ac[2][r]+tv2; v3[r]=ac[3][r]+tv3;
      ssq[r] = v0[r]*v0[r] + v1[r]*v1[r] + v2[r]*v2[r] + v3[r]*v3[r];
    }
#pragma unroll
    for (int off=1; off<32; off<<=1)
#pragma unroll
      for (int r=0;r<16;++r) ssq[r] += __shfl_xor(ssq[r], off, 64);
    if (l < 16) {
      int r = l;
      int grow = rw + (r&3) + 8*(r>>2) + 4*h;
      ynf[(r&3) + 8*(r>>2) + 4*h] = (grow >= 8191) ? -1.0e4f : KNEG * ssq[r];
    }
#pragma unroll
    for (int r=0;r<16;++r) {
      int rloc = (r&3) + 8*(r>>2) + 4*h;
      ytt[rloc*132 +   0 + l] = f2bf(KA2C * v0[r]);
      ytt[rloc*132 +  32 + l] = f2bf(KA2C * v1[r]);
      ytt[rloc*132 +  64 + l] = f2bf(KA2C * v2[r]);
      ytt[rloc*132 +  96 + l] = f2bf(KA2C * v3[r]);
    }
    __syncthreads();
    char* base = (char*)ctp + (size_t)T*T_STRIDE;
#pragma unroll
    for (int kc=0;kc<8;++kc) {
      const unsigned short* s = &ytt[l*132 + kc*16 + 8*h];
      uint2 a = *(const uint2*)(s);
      uint2 b = *(const uint2*)(s + 4);
      uint4 o; o.x=a.x; o.y=a.y; o.z=b.x; o.w=b.y;
      *(uint4*)(base + (jcw*9 + kc)*1024 + ln*16) = o;
    }
    {  // kc=8 slot: k=128 -> yn_hi, k=129 -> yn_lo (h=0 lanes only)
      float yn = ynf[l];
      unsigned short hi = f2bf(yn);
      float hif = __builtin_bit_cast(float, (unsigned)hi << 16);
      unsigned short lo = f2bf(yn - hif);
      uint4 o; o.x = (h == 0) ? ((unsigned)hi | ((unsigned)lo << 16)) : 0u;
      o.y = 0u; o.z = 0u; o.w = 0u;
      *(uint4*)(base + (jcw*9 + 8)*1024 + ln*16) = o;
    }
  } else {
    // ---- V task: 32 X1-rows; tile T2=(task-256)>>1, half=(task-256)&1 ----
    unsigned short* xs = (unsigned short*)slice;         // [32][136] bf16 = 8704 B
    const int tv_ = task - 256;
    const int T2 = tv_ >> 1, half = tv_ & 1;
    const int xr0 = T2*64 + half*32 + 1;
    {
      int rl = ln >> 1, ch2 = ln & 1;
      int row = xr0 + rl; if (row > 8191) row = 8191;   // pad j has g=0
      const float* src = X + (size_t)row*128 + ch2*64;
      unsigned short* dst = xs + rl*136 + ch2*64;
#pragma unroll
      for (int i=0;i<8;++i) {
        float4 p0 = *(const float4*)(src + i*8);
        float4 p1 = *(const float4*)(src + i*8 + 4);
        uint4 w;
        w.x = pk2bf(p0.x, p0.y); w.y = pk2bf(p0.z, p0.w);
        w.z = pk2bf(p1.x, p1.y); w.w = pk2bf(p1.z, p1.w);
        *(uint4*)(dst + i*8) = w;
      }
    }
    __syncthreads();
    char* base = (char*)ctp + (size_t)T2*T_STRIDE + V_OFF;
#pragma unroll
    for (int ch=0; ch<8; ++ch) {
      int jcl = ch >> 2, cc = ch & 3;
      int lr0 = jcl*16 + 8*h;
      int c = cc*32 + l;
      uint4 o;
      o.x = (unsigned)xs[(lr0+0)*136 + c] | ((unsigned)xs[(lr0+1)*136 + c] << 16);
      o.y = (unsigned)xs[(lr0+2)*136 + c] | ((unsigned)xs[(lr0+3)*136 + c] << 16);
      o.z = (unsigned)xs[(lr0+4)*136 + c] | ((unsigned)xs[(lr0+5)*136 + c] << 16);
      o.w = (unsigned)xs[(lr0+6)*136 + c] | ((unsigned)xs[(lr0+7)*136 + c] << 16);
      int jc16 = half*2 + jcl;
      *(uint4*)(base + (jc16*4 + cc)*1024 + ln*16) = o;
    }
  }
}

// ---------------- K_main (round-9: full dbuf, 1 barrier/tile) ----------------
// grid (64, js); block 256 = 4 waves x 32 query rows (BM=128); 2 blocks/CU.
// Per tile: issue full stage(T+1 -> other buf) ; S0 S1 exp0 exp1 PV0 PV1 from
// cur buf ; BAR (vmcnt0 drains stage, covered by the whole tile's compute).
// Hazards: other-buf's last readers finished before the PREVIOUS barrier;
// cur-buf was staged last tile and drained at that same barrier.
__global__ __launch_bounds__(256, 2) void k_main(
    const float* __restrict__ X,
    const unsigned short* __restrict__ ctp,
    float* __restrict__ accp,
    float* __restrict__ rsp,
    int js) {
  __shared__ unsigned short stg[2][T_STRIDE/2];   // 2 x 34816 B
  const int tid = threadIdx.x;
  const int wv = tid >> 6, ln = tid & 63;
  const int l = ln & 31, h = ln >> 5;
  const int row = blockIdx.x*128 + wv*32 + l;  // query row, always < 8192

  bf16x8 qf[9];  // Q as B-operand: x[row][k], plus k=128,129 -> 1,1 (h=0)
  {
    const float* xr = X + (size_t)row * 128;
#pragma unroll
    for (int kc=0;kc<8;++kc) {
      float4 p0 = *(const float4*)(xr + kc*16 + 8*h);
      float4 p1 = *(const float4*)(xr + kc*16 + 8*h + 4);
      qf[kc] = pack8(p0, p1);
    }
    uint4 o; o.x = (h == 0) ? 0x3F803F80u : 0u; o.y = 0u; o.z = 0u; o.w = 0u;
    qf[8] = __builtin_bit_cast(bf16x8, o);
  }
  f32x16 acc[4];
#pragma unroll
  for (int cc=0;cc<4;++cc)
#pragma unroll
    for (int i=0;i<16;++i) acc[cc][i]=0.f;
  float rs = 0.f;
  const int sp = blockIdx.y;
  const int Tbeg = (sp * 128) / js;
  const int Tend = ((sp + 1) * 128) / js;

  // softmax-exp of one S quadrant -> packed bf16 pair words
  auto dosm = [&](const f32x16& sa, unsigned wx[4], unsigned wy[4]) {
#pragma unroll
    for (int rg=0; rg<4; ++rg) {
      float g0 = fast_exp2(sa[rg*4+0]);
      float g1 = fast_exp2(sa[rg*4+1]);
      float g2 = fast_exp2(sa[rg*4+2]);
      float g3 = fast_exp2(sa[rg*4+3]);
      rs += (g0+g1) + (g2+g3);
      wx[rg] = pk2bf(g0, g1);
      wy[rg] = pk2bf(g2, g3);
    }
  };
  // PV for one jc: permlane32_swap redistributes packed P words in-register.
  auto dopv = [&](const char* sb, int jcb, unsigned wx[4], unsigned wy[4]) {
#pragma unroll
    for (int jj=0; jj<2; ++jj) {
      unsigned ax = wx[2*jj], bx = wx[2*jj+1];
      unsigned ay = wy[2*jj], by = wy[2*jj+1];
      pl32swap(ax, bx);
      pl32swap(ay, by);
      uint4 gv; gv.x = ax; gv.y = ay; gv.z = bx; gv.w = by;
      bf16x8 pb = __builtin_bit_cast(bf16x8, gv);
#pragma unroll
      for (int cc=0;cc<4;++cc) {
        bf16x8 a2 = *(const bf16x8*)(sb + V_OFF + ((jcb+jj)*4+cc)*1024 + ln*16);
        acc[cc] = mfma_32x32x16(a2, pb, acc[cc]);
      }
    }
  };

  // prologue: stage full tile Tbeg into buffer 0 (34 chunks of 1 KB)
  {
    const char* cb = (const char*)ctp + (size_t)Tbeg*T_STRIDE;
#pragma unroll
    for (int i=0;i<9;++i) {
      int c = wv + 4*i;
      if (c < 34) gl2lds16(cb + c*1024 + ln*16, (char*)stg + c*1024);
    }
  }
  __syncthreads();  // drain prologue stage

  int cur = 0;
  for (int T = Tbeg; T < Tend; ++T) {
    const char* sb = (const char*)stg + cur*T_STRIDE;
    if (T+1 < Tend) {   // issue entire next-tile stage into the other buffer
      const char* nb = (const char*)ctp + (size_t)(T+1)*T_STRIDE;
      char* sn = (char*)stg + (cur^1)*T_STRIDE;
#pragma unroll
      for (int i=0;i<9;++i) {
        int c = wv + 4*i;
        if (c < 34) gl2lds16(nb + c*1024 + ln*16, sn + c*1024);
      }
    }

    f32x16 sa0, sa1;
#pragma unroll
    for (int i=0;i<16;++i) { sa0[i]=0.f; sa1[i]=0.f; }
#pragma unroll
    for (int kc=0;kc<9;++kc) {
      bf16x8 a0 = *(const bf16x8*)(sb + kc*1024 + ln*16);
      sa0 = mfma_32x32x16(a0, qf[kc], sa0);
    }
#pragma unroll
    for (int kc=0;kc<9;++kc) {
      bf16x8 a1 = *(const bf16x8*)(sb + (9+kc)*1024 + ln*16);
      sa1 = mfma_32x32x16(a1, qf[kc], sa1);
    }
    unsigned wx0[4], wy0[4], wx1[4], wy1[4];
    dosm(sa0, wx0, wy0);
    dosm(sa1, wx1, wy1);
    dopv(sb, 0, wx0, wy0);     // PV jc=0: 8 MFMAs (V-lo)
    dopv(sb, 2, wx1, wy1);     // PV jc=1: 8 MFMAs (V-hi)

    __syncthreads();   // all reads of cur done; next-tile stage drained
    cur ^= 1;
  }
  rs += __shfl_xor(rs, 32, 64);
  if (h == 0) rsp[(size_t)sp*8192 + row] = rs;
  // acc^T: lane holds out^T[c = cc*32+(r&3)+8(r>>2)+4h][m = row]; store [sp][c][row]
#pragma unroll
  for (int cc=0;cc<4;++cc)
#pragma unroll
    for (int r=0;r<16;++r) {
      int c = cc*32 + (r&3) + 8*(r>>2) + 4*h;
      accp[((size_t)sp*128 + c)*8192 + row] = acc[cc][r];
    }
}

// ---------------- K_fin: pipelined split-reduce + normalize + transpose --------
// grid (128, 4) = 512 blocks (2/CU). Block: 64 rows x 32 cols.
// Thread: rows rq*4..+3 (r-contig float4), cols c0 + cg*2..+1. sp-loop unroll 4
// -> 8 float4 loads in flight per thread.
__global__ __launch_bounds__(256) void k_fin(const float* __restrict__ accp,
                                             const float* __restrict__ rsp,
                                             float* __restrict__ out,
                                             int js) {
  __shared__ float tr[64*36];   // stride 36 floats (144 B, 16B-aligned rows)
  __shared__ float rinv[64];
  const int tid = threadIdx.x;
  const int r0 = blockIdx.x * 64;
  const int c0 = blockIdx.y * 32;
  if (tid < 64) {
    float s = 0.f;
    for (int sp=0; sp<js; ++sp) s += rsp[(size_t)sp*8192 + r0 + tid];
    rinv[tid] = 1.f / s;
  }
  const int rq = tid & 15, cg = tid >> 4;   // rows rq*4..+3, cols c0+cg*2..+1
  float v[2][4];
#pragma unroll
  for (int cc=0;cc<2;++cc)
#pragma unroll
    for (int k=0;k<4;++k) v[cc][k]=0.f;
#pragma unroll 4
  for (int sp=0; sp<js; ++sp) {
    const float* base = accp + ((size_t)sp*128 + c0 + cg*2)*8192 + r0 + rq*4;
    float4 p0 = *(const float4*)(base);
    float4 p1 = *(const float4*)(base + 8192);
    v[0][0]+=p0.x; v[0][1]+=p0.y; v[0][2]+=p0.z; v[0][3]+=p0.w;
    v[1][0]+=p1.x; v[1][1]+=p1.y; v[1][2]+=p1.z; v[1][3]+=p1.w;
  }
  __syncthreads();
#pragma unroll
  for (int cc=0;cc<2;++cc)
#pragma unroll
    for (int k=0;k<4;++k)
      tr[(rq*4+k)*36 + cg*2+cc] = v[cc][k] * rinv[rq*4+k];
  __syncthreads();
  {
    int r = tid >> 2, q = tid & 3;   // 64 rows x 4 col-groups of 8
    int grow = r0 + r;
    if (grow < 8191) {
      float* dst = out + (size_t)grow*128 + c0 + q*8;
      const float* s2 = &tr[r*36 + q*8];
      *(float4*)(dst)     = *(const float4*)(s2);
      *(float4*)(dst + 4) = *(const float4*)(s2 + 4);
    }
  }
}

extern "C" void kernel_launch(void* const* d_in, const int* in_sizes, int n_in,
                              void* d_out, int out_size, void* d_ws, size_t ws_size,
                              hipStream_t stream) {
  const float* X = (const float*)d_in[0];
  const float* y = (const float*)d_in[1];
  // d_in[2] = y_next (unused by reference)
  const float* R = (const float*)d_in[3];
  const float* t = (const float*)d_in[4];
  float* out = (float*)d_out;
  char* ws = (char*)d_ws;

  unsigned short* ctp = (unsigned short*)ws;                 // 128 * 34816 = 4.456 MB
  size_t rspoff = (size_t)128 * T_STRIDE;
  float* rsp  = (float*)(ws + rspoff);                       // js*32 KB
  size_t accoff = rspoff + 512*1024;
  float* accp = (float*)(ws + accoff);                       // js * 4 MB

  int js = 8;  // 64 x 8 = 512 blocks = exactly 2 blocks/CU (LDS-capped by dbuf)
  while (js > 1 && accoff + (size_t)js*128*8192*4 > ws_size) js >>= 1;

  k_prep<<<dim3(512), dim3(64), 0, stream>>>(y, R, t, X, ctp);
  k_main<<<dim3(64, js), dim3(256), 0, stream>>>(X, ctp, accp, rsp, js);
  k_fin<<<dim3(128, 4), dim3(256), 0, stream>>>(accp, rsp, out, js);
}